// Round 11
// baseline (20.895 us; speedup 1.0000x reference)
//
#include <hip/hip_runtime.h>
#include <math.h>

#define B_    48
#define N_    512
#define NBOND 4096
#define H_    8
#define L_    2
#define G_    16                      // blocks per batch in bond pass
#define TPB1  256                     // 1 bond per thread
#define BPB   (NBOND / G_)            // 256 bonds per block
#define NW1   (TPB1 / 64)             // 4 waves per bond block
#define AB_   2                       // atom blocks per batch
#define TPB2  256                     // atoms per atom-block

#define LOG2E 1.44269504f

typedef float f32x2 __attribute__((ext_vector_type(2)));

__device__ __forceinline__ f32x2 splat2(float v) { f32x2 r; r.x = v; r.y = v; return r; }

__device__ __forceinline__ float rcpf(float x)  { return __builtin_amdgcn_rcpf(x); }
__device__ __forceinline__ float exp2g(float x) { return __builtin_amdgcn_exp2f(x); }
__device__ __forceinline__ float log2g(float x) { return __builtin_amdgcn_logf(x); }
__device__ __forceinline__ float expg(float x)  { return exp2g(x * LOG2E); }
__device__ __forceinline__ float sigf(float x)  { return rcpf(1.0f + expg(-x)); }

__device__ __forceinline__ float taperf(float r) {
    const float rmin = 0.001f, rmax = 0.002f;
    const float d = rmin - rmax;
    const float rterm = 1.0f / (d * d * d);
    float r3  = (r > rmax) ? 1.0f : 0.0f;
    bool ok   = (r <= rmax) && (r > rmin);
    float r2  = ok ? r : 0.0f;
    float r20 = ok ? 1.0f : 0.0f;
    float rm   = rmin * r20;
    float rd   = rm - r2;
    float trm1 = rm + 2.0f * r2 - 3.0f * rmax * r20;
    return rterm * rd * rd * trm1 + r3;
}

__global__ __launch_bounds__(TPB1) void bond_kernel(
    const float* __restrict__ x, const float* __restrict__ cell, const float* __restrict__ rcell,
    const int*  __restrict__ bdid,
    const float* __restrict__ rosi, const float* __restrict__ bo1, const float* __restrict__ bo2,
    const float* __restrict__ ropi, const float* __restrict__ bo3, const float* __restrict__ bo4,
    const float* __restrict__ ropp, const float* __restrict__ bo5, const float* __restrict__ bo6,
    const float* __restrict__ Desi,
    const float* __restrict__ wi, const float* __restrict__ w, const float* __restrict__ bvec,
    const float* __restrict__ wo, const float* __restrict__ bo_out,
    float2* __restrict__ pPart, float* __restrict__ pEbd)
{
    const int b   = blockIdx.x / G_;
    const int g   = blockIdx.x % G_;
    const int tid = threadIdx.x;

    __shared__ float sS[N_], sP[N_];          // bosi-scatter, bpi-scatter

    sS[tid] = 0.0f;        sP[tid] = 0.0f;
    sS[tid + TPB1] = 0.0f; sP[tid + TPB1] = 0.0f;

    float c00 = cell[0], c01 = cell[1], c02 = cell[2];
    float c10 = cell[3], c11 = cell[4], c12 = cell[5];
    float c20 = cell[6], c21 = cell[7], c22 = cell[8];
    float q00 = rcell[0], q01 = rcell[1], q02 = rcell[2];
    float q10 = rcell[3], q11 = rcell[4], q12 = rcell[5];
    float q20 = rcell[6], q21 = rcell[7], q22 = rcell[8];

    const float* xb = x + (size_t)b * (N_ * 3);

    // ---- bond phase: 1 bond per thread; t is wave-uniform -> scalarize ----
    int k = g * BPB + tid;
    int t = (k < 1600) ? 0 : ((k < 3200) ? 1 : 2);
    const int ts = __builtin_amdgcn_readfirstlane(t);

    float lro_si = log2g(rosi[ts]);
    float lro_pi = log2g(ropi[ts]);
    float lro_pp = log2g(ropp[ts]);
    float cb1 = bo1[ts] * LOG2E;
    float cb3 = bo3[ts] * LOG2E;
    float cb5 = bo5[ts] * LOG2E;
    float pw2 = bo2[ts], pw4 = bo4[ts], pw6 = bo6[ts];
    float des = Desi[ts];

    int2 ij = ((const int2*)bdid)[k];
    int i = ij.x, j = ij.y;

    float vx = xb[3 * i + 0] - xb[3 * j + 0];
    float vy = xb[3 * i + 1] - xb[3 * j + 1];
    float vz = xb[3 * i + 2] - xb[3 * j + 2];

    float f0 = vx * q00 + vy * q10 + vz * q20;
    float f1 = vx * q01 + vy * q11 + vz * q21;
    float f2 = vx * q02 + vy * q12 + vz * q22;
    f0 = (f0 - 0.5f > 0.0f) ? f0 - 1.0f : f0;  f0 = (f0 + 0.5f < 0.0f) ? f0 + 1.0f : f0;
    f1 = (f1 - 0.5f > 0.0f) ? f1 - 1.0f : f1;  f1 = (f1 + 0.5f < 0.0f) ? f1 + 1.0f : f1;
    f2 = (f2 - 0.5f > 0.0f) ? f2 - 1.0f : f2;  f2 = (f2 + 0.5f < 0.0f) ? f2 + 1.0f : f2;
    float wx = f0 * c00 + f1 * c10 + f2 * c20;
    float wy = f0 * c01 + f1 * c11 + f2 * c21;
    float wz = f0 * c02 + f1 * c12 + f2 * c22;
    float r = __builtin_amdgcn_sqrtf(wx * wx + wy * wy + wz * wz);

    float lr = log2g(r);
    float p1 = exp2g(pw2 * (lr - lro_si));
    float p2 = exp2g(pw4 * (lr - lro_pi));
    float p3 = exp2g(pw6 * (lr - lro_pp));
    float e1 = 1.001f * exp2g(cb1 * p1);
    float e2 = exp2g(cb3 * p2);
    float e3 = exp2g(cb5 * p3);
    float bosi = taperf(e1) * (e1 - 0.001f);
    float bopi = taperf(e2) * e2;
    float bopp = taperf(e3) * e3;

    // ---- MLP, packed over ho-pairs (weights wave-uniform -> SGPR pairs) ----
    const f32x2* Wi2 = (const f32x2*)(wi  + ts * 24);            // [3][4 pairs]
    const f32x2* Wm2 = (const f32x2*)(w   + ts * (L_ * H_ * H_)); // [l][hi][4]
    const f32x2* Bv2 = (const f32x2*)(bvec + ts * (L_ * H_));     // [l][4]
    const f32x2* Wo2 = (const f32x2*)(wo  + ts * H_);             // [4]

    float h[H_];
    #pragma unroll
    for (int p = 0; p < 4; ++p) {
        f32x2 s2 = splat2(bosi) * Wi2[p]
                 + splat2(bopi) * Wi2[4 + p]
                 + splat2(bopp) * Wi2[8 + p];
        h[2 * p]     = sigf(s2.x);
        h[2 * p + 1] = sigf(s2.y);
    }
    #pragma unroll
    for (int l = 0; l < L_; ++l) {
        float hn[H_];
        #pragma unroll
        for (int p = 0; p < 4; ++p) {
            f32x2 s2 = Bv2[l * 4 + p];
            #pragma unroll
            for (int hi = 0; hi < H_; ++hi)
                s2 += splat2(h[hi]) * Wm2[(l * H_ + hi) * 4 + p];
            hn[2 * p]     = sigf(s2.x);
            hn[2 * p + 1] = sigf(s2.y);
        }
        #pragma unroll
        for (int hh = 0; hh < H_; ++hh) h[hh] = hn[hh];
    }
    f32x2 oacc = splat2(h[0]) * Wo2[0];
    oacc += splat2(h[2]) * Wo2[1];
    oacc += splat2(h[4]) * Wo2[2];
    oacc += splat2(h[6]) * Wo2[3];
    // careful: Wo2[p] = (wo[2p], wo[2p+1]); pair with h[2p], h[2p+1]
    float o = bo_out[ts]
            + h[0] * ((const float*)wo)[ts * H_ + 0];
    // (recompute cleanly below to avoid pairing mistakes)
    {
        const float* Wo = wo + ts * H_;
        o = bo_out[ts];
        #pragma unroll
        for (int hi = 0; hi < H_; ++hi) o += h[hi] * Wo[hi];
    }
    float ebd = -des * sigf(o);

    float bpi = bopi + bopp;
    __syncthreads();                      // zeroing complete before atomics
    atomicAdd(&sS[i], bosi); atomicAdd(&sS[j], bosi);
    atomicAdd(&sP[i], bpi);  atomicAdd(&sP[j], bpi);
    __syncthreads();                      // atomics complete before readback

    // ---- packed float2 partial writes: slice (b*G+g) ----
    float2* pd = pPart + (size_t)(b * G_ + g) * N_;
    pd[tid]        = make_float2(sS[tid],        sP[tid]);
    pd[tid + TPB1] = make_float2(sS[tid + TPB1], sP[tid + TPB1]);

    // per-wave ebond partial (no extra barrier)
    float v = ebd;
    for (int off = 32; off > 0; off >>= 1) v += __shfl_down(v, off, 64);
    int lane = tid & 63, wid = tid >> 6;
    if (lane == 0) pEbd[(b * G_ + g) * NW1 + wid] = v;
}

__global__ __launch_bounds__(TPB2) void atom_kernel(
    const int* __restrict__ atype,
    const float* __restrict__ sval, const float* __restrict__ svale, const float* __restrict__ slp2,
    const float* __restrict__ sov2, const float* __restrict__ sov5,
    const float2* __restrict__ pPart, const float* __restrict__ pEbd,
    float* __restrict__ out)
{
    const int b   = blockIdx.x / AB_;
    const int c   = blockIdx.x % AB_;
    const int tid = threadIdx.x;
    const int a   = c * TPB2 + tid;            // atom index in [0, 512)
    __shared__ float swave[TPB2 / 64];

    float so = 0.0f, DP = 0.0f;
    #pragma unroll
    for (int g = 0; g < G_; ++g) {
        float2 v = pPart[(size_t)(b * G_ + g) * N_ + a];
        so += v.x;
        DP += v.y;
    }
    float D = so + DP;                         // Delta = SO + Delta_pi

    int at = atype[a];
    float val  = sval[at];
    float vale = svale[at];
    float lp2  = slp2[at];
    float ov2  = sov2[at];
    float ov5  = sov5[at];

    float Nlp = 0.5f * (vale - val);
    float de  = 0.5f * (D - vale);
    float De  = fminf(ceilf(de), 0.0f);
    float t1  = 1.0f + de - De;
    float nlp = -De + expg(-40.0f * t1 * t1);
    float Dlp = fmaxf(Nlp - nlp + 1.0f, 0.0f) - 1.0f;
    float Elone = lp2 * Dlp * rcpf(1.0f + expg(-75.0f * Dlp));

    float dlc = D - val - Dlp * rcpf(1.0f + 5.0f * expg(3.0f * DP));
    float denom = dlc + val;
    float ot = rcpf((denom != 0.0f) ? denom : 1e-8f);
    float Eover = so * ot * dlc * sigf(-ov2 * dlc);

    float expeu1 = expg(6.0f * dlc);
    float eu1 = sigf(ov2 * dlc);
    float eu2 = rcpf(1.0f + expg(12.0f * DP));
    float Eunder = -ov5 * (1.0f - expeu1) * eu1 * eu2;

    float e = Elone + Eover + Eunder;
    if (c == 0 && tid < G_ * NW1) e += pEbd[b * (G_ * NW1) + tid];  // 64 wave-partials

    float v = e;
    for (int off = 32; off > 0; off >>= 1) v += __shfl_down(v, off, 64);
    int lane = tid & 63, wid = tid >> 6;
    if (lane == 0) swave[wid] = v;
    __syncthreads();
    if (tid == 0) {
        float s = 0.0f;
        #pragma unroll
        for (int wv = 0; wv < TPB2 / 64; ++wv) s += swave[wv];
        atomicAdd(&out[b], s);
    }
}

extern "C" void kernel_launch(void* const* d_in, const int* in_sizes, int n_in,
                              void* d_out, int out_size, void* d_ws, size_t ws_size,
                              hipStream_t stream)
{
    const float* x     = (const float*)d_in[0];
    const float* cell  = (const float*)d_in[1];
    const float* rcell = (const float*)d_in[2];
    const int*   bdid  = (const int*)d_in[3];
    const int*   atype = (const int*)d_in[4];
    const float* rosi  = (const float*)d_in[5];
    const float* bo1   = (const float*)d_in[6];
    const float* bo2   = (const float*)d_in[7];
    const float* ropi  = (const float*)d_in[8];
    const float* bo3   = (const float*)d_in[9];
    const float* bo4   = (const float*)d_in[10];
    const float* ropp  = (const float*)d_in[11];
    const float* bo5   = (const float*)d_in[12];
    const float* bo6   = (const float*)d_in[13];
    const float* Desi  = (const float*)d_in[14];
    const float* sval  = (const float*)d_in[15];
    const float* svale = (const float*)d_in[16];
    const float* slp2  = (const float*)d_in[17];
    const float* sov2  = (const float*)d_in[18];
    const float* sov5  = (const float*)d_in[19];
    const float* wi    = (const float*)d_in[20];
    const float* w     = (const float*)d_in[21];
    const float* bvec  = (const float*)d_in[22];
    const float* wo    = (const float*)d_in[23];
    const float* bo_o  = (const float*)d_in[24];
    float* out = (float*)d_out;

    float2* pPart = (float2*)d_ws;                           // B*G*N float2
    float*  pEbd  = (float*)(pPart + (size_t)B_ * G_ * N_);  // B*G*NW1 floats

    hipMemsetAsync(out, 0, B_ * sizeof(float), stream);

    bond_kernel<<<B_ * G_, TPB1, 0, stream>>>(
        x, cell, rcell, bdid,
        rosi, bo1, bo2, ropi, bo3, bo4, ropp, bo5, bo6, Desi,
        wi, w, bvec, wo, bo_o,
        pPart, pEbd);

    atom_kernel<<<B_ * AB_, TPB2, 0, stream>>>(
        atype, sval, svale, slp2, sov2, sov5,
        pPart, pEbd, out);
}

// Round 12
// 16.203 us; speedup vs baseline: 1.2896x; 1.2896x over previous
//
#include <hip/hip_runtime.h>
#include <math.h>

#define B_    48
#define N_    512
#define NBOND 4096
#define H_    8
#define L_    2
#define G_    16                      // blocks per batch in bond pass
#define TPB1  256                     // 1 bond per thread
#define BPB   (NBOND / G_)            // 256 bonds per block
#define NW1   (TPB1 / 64)             // 4 waves per bond block
#define TPB2  512

#define LOG2E 1.44269504f

__device__ __forceinline__ float rcpf(float x)  { return __builtin_amdgcn_rcpf(x); }
__device__ __forceinline__ float exp2g(float x) { return __builtin_amdgcn_exp2f(x); }
__device__ __forceinline__ float log2g(float x) { return __builtin_amdgcn_logf(x); }
__device__ __forceinline__ float expg(float x)  { return exp2g(x * LOG2E); }
__device__ __forceinline__ float sigf(float x)  { return rcpf(1.0f + expg(-x)); }

__device__ __forceinline__ float taperf(float r) {
    const float rmin = 0.001f, rmax = 0.002f;
    const float d = rmin - rmax;
    const float rterm = 1.0f / (d * d * d);
    float r3  = (r > rmax) ? 1.0f : 0.0f;
    bool ok   = (r <= rmax) && (r > rmin);
    float r2  = ok ? r : 0.0f;
    float r20 = ok ? 1.0f : 0.0f;
    float rm   = rmin * r20;
    float rd   = rm - r2;
    float trm1 = rm + 2.0f * r2 - 3.0f * rmax * r20;
    return rterm * rd * rd * trm1 + r3;
}

__global__ __launch_bounds__(TPB1) void bond_kernel(
    const float* __restrict__ x, const float* __restrict__ cell, const float* __restrict__ rcell,
    const int*  __restrict__ bdid,
    const float* __restrict__ rosi, const float* __restrict__ bo1, const float* __restrict__ bo2,
    const float* __restrict__ ropi, const float* __restrict__ bo3, const float* __restrict__ bo4,
    const float* __restrict__ ropp, const float* __restrict__ bo5, const float* __restrict__ bo6,
    const float* __restrict__ Desi,
    const float* __restrict__ wi, const float* __restrict__ w, const float* __restrict__ bvec,
    const float* __restrict__ wo, const float* __restrict__ bo_out,
    float2* __restrict__ pPart, float* __restrict__ pEbd)
{
    const int b   = blockIdx.x / G_;
    const int g   = blockIdx.x % G_;
    const int tid = threadIdx.x;

    __shared__ float sS[N_], sP[N_];          // bosi-scatter, bpi-scatter
    __shared__ float4 sX[N_];                 // padded xyz per atom

    sS[tid] = 0.0f;        sP[tid] = 0.0f;
    sS[tid + TPB1] = 0.0f; sP[tid + TPB1] = 0.0f;

    const float* xb = x + (size_t)b * (N_ * 3);
    // stage positions: 2 atoms per thread, coalesced-contiguous source
    {
        int a0 = tid, a1 = tid + TPB1;
        sX[a0] = make_float4(xb[3 * a0], xb[3 * a0 + 1], xb[3 * a0 + 2], 0.0f);
        sX[a1] = make_float4(xb[3 * a1], xb[3 * a1 + 1], xb[3 * a1 + 2], 0.0f);
    }

    float c00 = cell[0], c01 = cell[1], c02 = cell[2];
    float c10 = cell[3], c11 = cell[4], c12 = cell[5];
    float c20 = cell[6], c21 = cell[7], c22 = cell[8];
    float q00 = rcell[0], q01 = rcell[1], q02 = rcell[2];
    float q10 = rcell[3], q11 = rcell[4], q12 = rcell[5];
    float q20 = rcell[6], q21 = rcell[7], q22 = rcell[8];

    // ---- bond phase: 1 bond per thread; t is wave-uniform -> scalarize ----
    int k = g * BPB + tid;
    int t = (k < 1600) ? 0 : ((k < 3200) ? 1 : 2);
    const int ts = __builtin_amdgcn_readfirstlane(t);

    float lro_si = log2g(rosi[ts]);
    float lro_pi = log2g(ropi[ts]);
    float lro_pp = log2g(ropp[ts]);
    float cb1 = bo1[ts] * LOG2E;
    float cb3 = bo3[ts] * LOG2E;
    float cb5 = bo5[ts] * LOG2E;
    float pw2 = bo2[ts], pw4 = bo4[ts], pw6 = bo6[ts];
    float des = Desi[ts];

    int2 ij = ((const int2*)bdid)[k];
    int i = ij.x, j = ij.y;

    __syncthreads();                      // staging + zeroing complete

    float4 xi = sX[i], xj = sX[j];
    float vx = xi.x - xj.x;
    float vy = xi.y - xj.y;
    float vz = xi.z - xj.z;

    float f0 = vx * q00 + vy * q10 + vz * q20;
    float f1 = vx * q01 + vy * q11 + vz * q21;
    float f2 = vx * q02 + vy * q12 + vz * q22;
    f0 = (f0 - 0.5f > 0.0f) ? f0 - 1.0f : f0;  f0 = (f0 + 0.5f < 0.0f) ? f0 + 1.0f : f0;
    f1 = (f1 - 0.5f > 0.0f) ? f1 - 1.0f : f1;  f1 = (f1 + 0.5f < 0.0f) ? f1 + 1.0f : f1;
    f2 = (f2 - 0.5f > 0.0f) ? f2 - 1.0f : f2;  f2 = (f2 + 0.5f < 0.0f) ? f2 + 1.0f : f2;
    float wx = f0 * c00 + f1 * c10 + f2 * c20;
    float wy = f0 * c01 + f1 * c11 + f2 * c21;
    float wz = f0 * c02 + f1 * c12 + f2 * c22;
    float r = __builtin_amdgcn_sqrtf(wx * wx + wy * wy + wz * wz);

    float lr = log2g(r);
    float p1 = exp2g(pw2 * (lr - lro_si));
    float p2 = exp2g(pw4 * (lr - lro_pi));
    float p3 = exp2g(pw6 * (lr - lro_pp));
    float e1 = 1.001f * exp2g(cb1 * p1);
    float e2 = exp2g(cb3 * p2);
    float e3 = exp2g(cb5 * p3);
    float bosi = taperf(e1) * (e1 - 0.001f);
    float bopi = taperf(e2) * e2;
    float bopp = taperf(e3) * e3;

    // MLP with wave-uniform (scalar) weight reads
    const float* Wi = wi + ts * 24;                 // [3][8]
    const float* Wm = w + ts * (L_ * H_ * H_);      // [L][8][8] (hi-major)
    const float* Bv = bvec + ts * (L_ * H_);
    const float* Wo = wo + ts * H_;

    float h[H_], h2[H_];
    #pragma unroll
    for (int hh = 0; hh < H_; ++hh) {
        float s = bosi * Wi[0 * H_ + hh] + bopi * Wi[1 * H_ + hh] + bopp * Wi[2 * H_ + hh];
        h[hh] = sigf(s);
    }
    #pragma unroll
    for (int l = 0; l < L_; ++l) {
        #pragma unroll
        for (int ho = 0; ho < H_; ++ho) {
            float s = Bv[l * H_ + ho];
            #pragma unroll
            for (int hi = 0; hi < H_; ++hi)
                s += h[hi] * Wm[l * (H_ * H_) + hi * H_ + ho];
            h2[ho] = sigf(s);
        }
        #pragma unroll
        for (int hh = 0; hh < H_; ++hh) h[hh] = h2[hh];
    }
    float o = bo_out[ts];
    #pragma unroll
    for (int hi = 0; hi < H_; ++hi) o += h[hi] * Wo[hi];
    float ebd = -des * sigf(o);

    float bpi = bopi + bopp;
    atomicAdd(&sS[i], bosi); atomicAdd(&sS[j], bosi);
    atomicAdd(&sP[i], bpi);  atomicAdd(&sP[j], bpi);
    __syncthreads();                      // atomics complete before readback

    // ---- packed float2 partial writes: slice (b*G+g) ----
    float2* pd = pPart + (size_t)(b * G_ + g) * N_;
    pd[tid]        = make_float2(sS[tid],        sP[tid]);
    pd[tid + TPB1] = make_float2(sS[tid + TPB1], sP[tid + TPB1]);

    // per-wave ebond partial (no extra barrier)
    float v = ebd;
    for (int off = 32; off > 0; off >>= 1) v += __shfl_down(v, off, 64);
    int lane = tid & 63, wid = tid >> 6;
    if (lane == 0) pEbd[(b * G_ + g) * NW1 + wid] = v;
}

__global__ __launch_bounds__(TPB2) void atom_kernel(
    const int* __restrict__ atype,
    const float* __restrict__ sval, const float* __restrict__ svale, const float* __restrict__ slp2,
    const float* __restrict__ sov2, const float* __restrict__ sov5,
    const float2* __restrict__ pPart, const float* __restrict__ pEbd,
    float* __restrict__ out)
{
    const int b   = blockIdx.x;
    const int tid = threadIdx.x;
    __shared__ float swave[TPB2 / 64];

    float so = 0.0f, DP = 0.0f;
    #pragma unroll
    for (int g = 0; g < G_; ++g) {
        float2 v = pPart[(size_t)(b * G_ + g) * N_ + tid];
        so += v.x;
        DP += v.y;
    }
    float D = so + DP;                         // Delta = SO + Delta_pi

    int at = atype[tid];
    float val  = sval[at];
    float vale = svale[at];
    float lp2  = slp2[at];
    float ov2  = sov2[at];
    float ov5  = sov5[at];

    float Nlp = 0.5f * (vale - val);
    float de  = 0.5f * (D - vale);
    float De  = fminf(ceilf(de), 0.0f);
    float t1  = 1.0f + de - De;
    float nlp = -De + expg(-40.0f * t1 * t1);
    float Dlp = fmaxf(Nlp - nlp + 1.0f, 0.0f) - 1.0f;
    float Elone = lp2 * Dlp * rcpf(1.0f + expg(-75.0f * Dlp));

    float dlc = D - val - Dlp * rcpf(1.0f + 5.0f * expg(3.0f * DP));
    float denom = dlc + val;
    float ot = rcpf((denom != 0.0f) ? denom : 1e-8f);
    float Eover = so * ot * dlc * sigf(-ov2 * dlc);

    float expeu1 = expg(6.0f * dlc);
    float eu1 = sigf(ov2 * dlc);
    float eu2 = rcpf(1.0f + expg(12.0f * DP));
    float Eunder = -ov5 * (1.0f - expeu1) * eu1 * eu2;

    float e = Elone + Eover + Eunder;
    if (tid < G_ * NW1) e += pEbd[b * (G_ * NW1) + tid];   // 64 wave-partials

    float v = e;
    for (int off = 32; off > 0; off >>= 1) v += __shfl_down(v, off, 64);
    int lane = tid & 63, wid = tid >> 6;
    if (lane == 0) swave[wid] = v;
    __syncthreads();
    if (tid == 0) {
        float s = 0.0f;
        #pragma unroll
        for (int wv = 0; wv < TPB2 / 64; ++wv) s += swave[wv];
        out[b] = s;
    }
}

extern "C" void kernel_launch(void* const* d_in, const int* in_sizes, int n_in,
                              void* d_out, int out_size, void* d_ws, size_t ws_size,
                              hipStream_t stream)
{
    const float* x     = (const float*)d_in[0];
    const float* cell  = (const float*)d_in[1];
    const float* rcell = (const float*)d_in[2];
    const int*   bdid  = (const int*)d_in[3];
    const int*   atype = (const int*)d_in[4];
    const float* rosi  = (const float*)d_in[5];
    const float* bo1   = (const float*)d_in[6];
    const float* bo2   = (const float*)d_in[7];
    const float* ropi  = (const float*)d_in[8];
    const float* bo3   = (const float*)d_in[9];
    const float* bo4   = (const float*)d_in[10];
    const float* ropp  = (const float*)d_in[11];
    const float* bo5   = (const float*)d_in[12];
    const float* bo6   = (const float*)d_in[13];
    const float* Desi  = (const float*)d_in[14];
    const float* sval  = (const float*)d_in[15];
    const float* svale = (const float*)d_in[16];
    const float* slp2  = (const float*)d_in[17];
    const float* sov2  = (const float*)d_in[18];
    const float* sov5  = (const float*)d_in[19];
    const float* wi    = (const float*)d_in[20];
    const float* w     = (const float*)d_in[21];
    const float* bvec  = (const float*)d_in[22];
    const float* wo    = (const float*)d_in[23];
    const float* bo_o  = (const float*)d_in[24];
    float* out = (float*)d_out;

    float2* pPart = (float2*)d_ws;                           // B*G*N float2
    float*  pEbd  = (float*)(pPart + (size_t)B_ * G_ * N_);  // B*G*NW1 floats

    bond_kernel<<<B_ * G_, TPB1, 0, stream>>>(
        x, cell, rcell, bdid,
        rosi, bo1, bo2, ropi, bo3, bo4, ropp, bo5, bo6, Desi,
        wi, w, bvec, wo, bo_o,
        pPart, pEbd);

    atom_kernel<<<B_, TPB2, 0, stream>>>(
        atype, sval, svale, slp2, sov2, sov5,
        pPart, pEbd, out);
}